// Round 2
// baseline (45710.767 us; speedup 1.0000x reference)
//
#include <hip/hip_runtime.h>
#include <math.h>

// ---------------------------------------------------------------------------
// Seq2Seq LSTM (S=128,B=64,I=H=O=1024,L=2,T=64) on gfx950.
// Round 2: split-K fan-in stage kernel.
//   stage = gates[64,4096] = A0[64,1024]@W0^T + A1[64,1024]@W1^T + b ; cell.
//   256 blocks/stage = 64 col-tiles (16 h-cols x 4 gates) x 4 K-chunks(512).
//   Block: 8 waves, each owns K=64 slice -> no intra-block A duplication.
//   LDS 8-slice reduce -> fp32 partial store -> threadfence + atomic counter
//   fan-in; last block of 4 sums partials + bias, runs LSTM cell, writes
//   split-bf16 h + fp32 c, resets counter. No spinning => dispatch-order safe.
// ---------------------------------------------------------------------------

typedef unsigned short u16;
typedef short short8 __attribute__((ext_vector_type(8)));
typedef float f32x4 __attribute__((ext_vector_type(4)));

#define MFMA_BF16 __builtin_amdgcn_mfma_f32_16x16x32_bf16

__device__ __forceinline__ u16 f2bf(float x) {
  unsigned u = __builtin_bit_cast(unsigned, x);
  unsigned r = u + 0x7fffu + ((u >> 16) & 1u);   // RNE (no NaN inputs here)
  return (u16)(r >> 16);
}
__device__ __forceinline__ float bf2f(u16 b) {
  return __builtin_bit_cast(float, ((unsigned)b) << 16);
}

// ---------------- prep kernels ----------------

__global__ void split_mat(const float* __restrict__ src, u16* __restrict__ dh,
                          u16* __restrict__ dl, int n, int C, int ldd, int trans) {
  int i = blockIdx.x * 256 + threadIdx.x;
  if (i >= n) return;
  float v = src[i];
  u16 hi = f2bf(v);
  u16 lo = f2bf(v - bf2f(hi));
  int r = i / C, c = i % C;
  int idx = trans ? (c * ldd + r) : (r * ldd + c);
  dh[idx] = hi; dl[idx] = lo;
}

__global__ void zero_f4(float4* __restrict__ p, int n) {
  int i = blockIdx.x * 256 + threadIdx.x;
  if (i < n) p[i] = make_float4(0.f, 0.f, 0.f, 0.f);
}

// bcomb[n] = dec_b0[n] + sum_k lin_b[k] * dec_wih0[n][k]
__global__ void bias_comb(const float* __restrict__ db0, const float* __restrict__ lb,
                          const float* __restrict__ wih, float* __restrict__ out) {
  __shared__ float red[256];
  int n = blockIdx.x;
  float s = 0.f;
  for (int k = threadIdx.x; k < 1024; k += 256) s += lb[k] * wih[(size_t)n * 1024 + k];
  red[threadIdx.x] = s;
  __syncthreads();
  for (int d = 128; d > 0; d >>= 1) {
    if (threadIdx.x < d) red[threadIdx.x] += red[threadIdx.x + d];
    __syncthreads();
  }
  if (threadIdx.x == 0) out[n] = db0[n] + red[0];
}

// ---------------- generic split-bf16 GEMM: C[M,N] = A[M,K] * B[N,K]^T ------
// mode 0: write split bf16 (hi/lo) to Ch/Cl (Wcomb build)
// mode 1: write fp32 + bias to outp with row=(t*64+b) -> out[b][t][col] scatter
__global__ __launch_bounds__(256) void gemm_split(
    const u16* __restrict__ Ah, const u16* __restrict__ Al, int lda,
    const u16* __restrict__ Bh, const u16* __restrict__ Bl, int ldb,
    int K, u16* __restrict__ Ch, u16* __restrict__ Cl, int ldc,
    float* __restrict__ outp, const float* __restrict__ bias, int mode, int gn) {
  int bm = blockIdx.x / gn, bn = blockIdx.x % gn;
  int l = threadIdx.x & 63, w = threadIdx.x >> 6;
  int n0 = bn * 64 + w * 16;
  int rr = l & 15, ko = (l >> 4) << 3;
  int nrow = n0 + rr;
  f32x4 acc[4] = {};
  for (int kk = 0; kk < K; kk += 32) {
    short8 bh = *(const short8*)(Bh + (size_t)nrow * ldb + kk + ko);
    short8 bl = *(const short8*)(Bl + (size_t)nrow * ldb + kk + ko);
#pragma unroll
    for (int mt = 0; mt < 4; ++mt) {
      size_t ao = (size_t)(bm * 64 + mt * 16 + rr) * lda + kk + ko;
      short8 ah = *(const short8*)(Ah + ao);
      short8 al = *(const short8*)(Al + ao);
      acc[mt] = MFMA_BF16(ah, bh, acc[mt], 0, 0, 0);
      acc[mt] = MFMA_BF16(ah, bl, acc[mt], 0, 0, 0);
      acc[mt] = MFMA_BF16(al, bh, acc[mt], 0, 0, 0);
    }
  }
  int q = l >> 4;
#pragma unroll
  for (int mt = 0; mt < 4; ++mt)
#pragma unroll
    for (int r = 0; r < 4; ++r) {
      int row = bm * 64 + mt * 16 + q * 4 + r;
      int col = n0 + rr;
      float v = acc[mt][r];
      if (mode == 0) {
        u16 hh = f2bf(v);
        Ch[(size_t)row * ldc + col] = hh;
        Cl[(size_t)row * ldc + col] = f2bf(v - bf2f(hh));
      } else {
        int t = row >> 6, b = row & 63;
        outp[(size_t)b * 65536 + t * 1024 + col] = v + bias[col];
      }
    }
}

// ---------------- split-K LSTM stage kernel ----------------

struct Op { const u16 *Ah, *Al, *Wh, *Wl; };
struct Stage {
  Op ops[2];           // op0: x-side (A[64][1024] @ W[4096][1024]^T), op1: h-side
  const float* bias;   // [4096]
  float* c;            // [64][1024] fp32, in-place
  u16 *Hh, *Hl;        // h out (split)
  u16 *Gh, *Gl;        // optional duplicate h dest (H1 history), may be null
  float* part;         // [4][64][4096] fp32 partials
  int* cnt;            // [64] fan-in counters (pre-zeroed)
  int active;
};

__global__ __launch_bounds__(512, 2) void lstm_stage(Stage s0, Stage s1, int nper) {
  bool first = ((int)blockIdx.x < nper);
  Stage S = first ? s0 : s1;
  if (!S.active) return;
  int bid = first ? blockIdx.x : (blockIdx.x - nper);
  int j = bid >> 2, kc = bid & 3;           // col-tile, K-chunk
  Op op = S.ops[kc >> 1];
  int kbase = (kc & 1) * 512;               // K offset within operand
  int tid = threadIdx.x;
  int l = tid & 63, w = tid >> 6;
  int rr = l & 15, ko = (l >> 4) << 3, q = l >> 4;
  int kw = kbase + w * 64;                  // this wave's K slice (64 wide)

  f32x4 acc[16] = {};                       // [mt][nt]
#pragma unroll
  for (int it = 0; it < 2; ++it) {
    int kk = kw + it * 32 + ko;
    short8 ah[4], al[4], bh[4], bl[4];
#pragma unroll
    for (int mt = 0; mt < 4; ++mt) {
      size_t ao = (size_t)(mt * 16 + rr) * 1024 + kk;
      ah[mt] = *(const short8*)(op.Ah + ao);
      al[mt] = *(const short8*)(op.Al + ao);
    }
#pragma unroll
    for (int nt = 0; nt < 4; ++nt) {
      size_t wo = (size_t)(nt * 1024 + (j << 4) + rr) * 1024 + kk;
      bh[nt] = *(const short8*)(op.Wh + wo);
      bl[nt] = *(const short8*)(op.Wl + wo);
    }
#pragma unroll
    for (int mt = 0; mt < 4; ++mt)
#pragma unroll
      for (int nt = 0; nt < 4; ++nt) {
        f32x4 t = acc[mt * 4 + nt];
        t = MFMA_BF16(ah[mt], bh[nt], t, 0, 0, 0);
        t = MFMA_BF16(ah[mt], bl[nt], t, 0, 0, 0);
        t = MFMA_BF16(al[mt], bh[nt], t, 0, 0, 0);
        acc[mt * 4 + nt] = t;
      }
  }

  // 8-slice LDS reduce (pad 66 to break bank alignment)
  __shared__ float lds[8][64][66];
  __shared__ int lastFlag;
#pragma unroll
  for (int mt = 0; mt < 4; ++mt)
#pragma unroll
    for (int nt = 0; nt < 4; ++nt)
#pragma unroll
      for (int r = 0; r < 4; ++r)
        lds[w][mt * 16 + q * 4 + r][nt * 16 + rr] = acc[mt * 4 + nt][r];
  __syncthreads();

  // reduce 8 slices; store fp32 partial [kc][row][gatecol]
  {
    int row = tid >> 3;
    int c0 = (tid & 7) * 8;                 // 8 consecutive cols, within one nt group
    float s8[8];
#pragma unroll
    for (int i = 0; i < 8; ++i) {
      float s = 0.f;
#pragma unroll
      for (int ww = 0; ww < 8; ++ww) s += lds[ww][row][c0 + i];
      s8[i] = s;
    }
    int nt = c0 >> 4, cc = c0 & 15;
    float* dst = S.part + (((size_t)kc * 64 + row) << 12) + nt * 1024 + (j << 4) + cc;
#pragma unroll
    for (int i = 0; i < 8; ++i) dst[i] = s8[i];
  }

  // fan-in: release partials, count arrivals; last block runs the cell
  __threadfence();
  if (tid == 0) {
    int old = atomicAdd(&S.cnt[j], 1);
    lastFlag = (old == 3) ? 1 : 0;
  }
  __syncthreads();
  if (!lastFlag) return;
  __threadfence();                           // acquire other blocks' partials

  for (int e = tid; e < 1024; e += 512) {
    int b = e >> 4, jj = e & 15;
    int col = (j << 4) + jj;
    float g[4];
#pragma unroll
    for (int gt = 0; gt < 4; ++gt) {
      float s = S.bias[gt * 1024 + col];
#pragma unroll
      for (int k2 = 0; k2 < 4; ++k2)
        s += S.part[(((size_t)k2 * 64 + b) << 12) + gt * 1024 + col];
      g[gt] = s;
    }
    size_t ci = (size_t)b * 1024 + col;
    float cold = S.c[ci];
    float is = 1.f / (1.f + expf(-g[0]));
    float fs = 1.f / (1.f + expf(-g[1]));
    float gt2 = tanhf(g[2]);
    float os = 1.f / (1.f + expf(-g[3]));
    float cn = fs * cold + is * gt2;
    S.c[ci] = cn;
    float h = os * tanhf(cn);
    u16 hh = f2bf(h);
    u16 hl = f2bf(h - bf2f(hh));
    S.Hh[ci] = hh; S.Hl[ci] = hl;
    if (S.Gh) { S.Gh[ci] = hh; S.Gl[ci] = hl; }
  }
  if (tid == 0) S.cnt[j] = 0;                // reset for the next stage (stream-ordered)
}

// ---------------- host ----------------

static inline Stage mkStage(const u16* a0h, const u16* a0l, const u16* w0h, const u16* w0l,
                            const u16* a1h, const u16* a1l, const u16* w1h, const u16* w1l,
                            const float* bias, float* c, u16* Hh, u16* Hl,
                            u16* Gh, u16* Gl, float* part, int* cnt, int act) {
  Stage s;
  s.ops[0] = {a0h, a0l, w0h, w0l};
  s.ops[1] = {a1h, a1l, w1h, w1l};
  s.bias = bias; s.c = c; s.Hh = Hh; s.Hl = Hl; s.Gh = Gh; s.Gl = Gl;
  s.part = part; s.cnt = cnt; s.active = act;
  return s;
}

extern "C" void kernel_launch(void* const* d_in, const int* in_sizes, int n_in,
                              void* d_out, int out_size, void* d_ws, size_t ws_size,
                              hipStream_t stream) {
  (void)in_sizes; (void)n_in; (void)out_size; (void)ws_size;
  const float* input_seq = (const float*)d_in[0];   // [128,64,1024]
  const float* enc_wih   = (const float*)d_in[1];   // [2,4096,1024]
  const float* enc_whh   = (const float*)d_in[2];
  const float* enc_b     = (const float*)d_in[3];   // [2,4096]
  const float* dec_wih   = (const float*)d_in[4];
  const float* dec_whh   = (const float*)d_in[5];
  const float* dec_b     = (const float*)d_in[6];
  const float* lin_w     = (const float*)d_in[7];   // [1024,1024]
  const float* lin_b     = (const float*)d_in[8];   // [1024]
  float* out = (float*)d_out;                       // [64,64,1024]

  const size_t WE = 4096ull * 1024;
  const size_t HB = 64ull * 1024;
  char* ws = (char*)d_ws;
  size_t off = 0;
  auto alloc16 = [&](size_t elems) {
    u16* p = (u16*)(ws + off);
    off = (off + elems * 2 + 255) & ~(size_t)255;
    return p;
  };
  auto allocf = [&](size_t elems) {
    float* p = (float*)(ws + off);
    off = (off + elems * 4 + 255) & ~(size_t)255;
    return p;
  };
  auto alloci = [&](size_t elems) {
    int* p = (int*)(ws + off);
    off = (off + elems * 4 + 255) & ~(size_t)255;
    return p;
  };

  u16 *WihE0h = alloc16(WE), *WihE0l = alloc16(WE);
  u16 *WhhE0h = alloc16(WE), *WhhE0l = alloc16(WE);
  u16 *WihE1h = alloc16(WE), *WihE1l = alloc16(WE);
  u16 *WhhE1h = alloc16(WE), *WhhE1l = alloc16(WE);
  u16 *WihD0h = alloc16(WE), *WihD0l = alloc16(WE);
  u16 *WhhD0h = alloc16(WE), *WhhD0l = alloc16(WE);
  u16 *WihD1h = alloc16(WE), *WihD1l = alloc16(WE);
  u16 *WhhD1h = alloc16(WE), *WhhD1l = alloc16(WE);
  u16 *Wcombh = alloc16(WE), *Wcombl = alloc16(WE);
  u16 *WLh  = alloc16(1024 * 1024), *WLl  = alloc16(1024 * 1024);
  u16 *WLTh = alloc16(1024 * 1024), *WLTl = alloc16(1024 * 1024);
  u16 *XSh = alloc16(8192ull * 1024), *XSl = alloc16(8192ull * 1024);
  u16 *H1h = alloc16(64 * HB), *H1l = alloc16(64 * HB);
  // ---- zeroed state region (contiguous): h ping-pongs, c, counters ----
  size_t zbeg = off;
  u16 *h0h = alloc16(2 * HB), *h0l = alloc16(2 * HB);
  u16 *h1h = alloc16(2 * HB), *h1l = alloc16(2 * HB);
  float *c0 = allocf(HB), *c1 = allocf(HB);
  int *cnt0 = alloci(64), *cnt1 = alloci(64);
  size_t zend = off;
  // ---- non-zeroed scratch ----
  float *part0 = allocf(4 * 64 * 4096);   // 4 MB
  float *part1 = allocf(4 * 64 * 4096);
  float *bdec0 = allocf(4096);

  // 1) zero state region
  {
    int n4 = (int)((zend - zbeg) / 16);
    zero_f4<<<dim3((n4 + 255) / 256), dim3(256), 0, stream>>>((float4*)(ws + zbeg), n4);
  }
  // 2) split inputs & weights
  auto split = [&](const float* src, u16* dh, u16* dl, int n, int trans) {
    split_mat<<<dim3((n + 255) / 256), dim3(256), 0, stream>>>(src, dh, dl, n, 1024, 1024, trans);
  };
  split(input_seq, XSh, XSl, 8192 * 1024, 0);
  split(enc_wih,        WihE0h, WihE0l, (int)WE, 0);
  split(enc_whh,        WhhE0h, WhhE0l, (int)WE, 0);
  split(enc_wih + WE,   WihE1h, WihE1l, (int)WE, 0);
  split(enc_whh + WE,   WhhE1h, WhhE1l, (int)WE, 0);
  split(dec_wih,        WihD0h, WihD0l, (int)WE, 0);
  split(dec_whh,        WhhD0h, WhhD0l, (int)WE, 0);
  split(dec_wih + WE,   WihD1h, WihD1l, (int)WE, 0);
  split(dec_whh + WE,   WhhD1h, WhhD1l, (int)WE, 0);
  split(lin_w, WLh,  WLl,  1024 * 1024, 0);
  split(lin_w, WLTh, WLTl, 1024 * 1024, 1);
  // 3) combined decoder-L0 bias
  bias_comb<<<dim3(4096), dim3(256), 0, stream>>>(dec_b, lin_b, dec_wih, bdec0);
  // 4) Wcomb[n][h] = sum_j dec_wih0[n][j] * lin_w[j][h]
  gemm_split<<<dim3(64 * 16), dim3(256), 0, stream>>>(
      WihD0h, WihD0l, 1024, WLTh, WLTl, 1024, 1024,
      Wcombh, Wcombl, 1024, nullptr, nullptr, 0, 16);

  // 5) encoder: pipelined L0(s) + L1(s-1), s = 0..128; 512 blocks/launch
  for (int s = 0; s <= 128; ++s) {
    int u = s - 1;
    Stage L0 = mkStage(
        XSh + (size_t)s * HB, XSl + (size_t)s * HB, WihE0h, WihE0l,
        h0h + ((s + 1) & 1) * HB, h0l + ((s + 1) & 1) * HB, WhhE0h, WhhE0l,
        enc_b, c0, h0h + (s & 1) * HB, h0l + (s & 1) * HB,
        nullptr, nullptr, part0, cnt0, s < 128 ? 1 : 0);
    Stage L1 = mkStage(
        h0h + (u & 1) * HB, h0l + (u & 1) * HB, WihE1h, WihE1l,
        h1h + ((u + 1) & 1) * HB, h1l + ((u + 1) & 1) * HB, WhhE1h, WhhE1l,
        enc_b + 4096, c1, h1h + (u & 1) * HB, h1l + (u & 1) * HB,
        nullptr, nullptr, part1, cnt1, s >= 1 ? 1 : 0);
    lstm_stage<<<dim3(512), dim3(512), 0, stream>>>(L0, L1, 256);
  }

  // 6) decoder: per step, stage A (L0, head folded) then stage B (L1)
  for (int t = 0; t < 64; ++t) {
    Stage A;
    if (t == 0) {
      A = mkStage(XSh + 127ull * HB, XSl + 127ull * HB, WihD0h, WihD0l,
                  h0h + ((t + 1) & 1) * HB, h0l + ((t + 1) & 1) * HB, WhhD0h, WhhD0l,
                  dec_b, c0, h0h + (t & 1) * HB, h0l + (t & 1) * HB,
                  nullptr, nullptr, part0, cnt0, 1);
    } else {
      A = mkStage(h1h + ((t - 1) & 1) * HB, h1l + ((t - 1) & 1) * HB, Wcombh, Wcombl,
                  h0h + ((t + 1) & 1) * HB, h0l + ((t + 1) & 1) * HB, WhhD0h, WhhD0l,
                  bdec0, c0, h0h + (t & 1) * HB, h0l + (t & 1) * HB,
                  nullptr, nullptr, part0, cnt0, 1);
    }
    lstm_stage<<<dim3(256), dim3(512), 0, stream>>>(A, A, 256);
    Stage Bst = mkStage(
        h0h + (t & 1) * HB, h0l + (t & 1) * HB, WihD1h, WihD1l,
        h1h + ((t + 1) & 1) * HB, h1l + ((t + 1) & 1) * HB, WhhD1h, WhhD1l,
        dec_b + 4096, c1, h1h + (t & 1) * HB, h1l + (t & 1) * HB,
        H1h + (size_t)t * HB, H1l + (size_t)t * HB, part1, cnt1, 1);
    lstm_stage<<<dim3(256), dim3(512), 0, stream>>>(Bst, Bst, 256);
  }

  // 7) y[b][t][o] = H1[t*64+b][:] . lin_w[o][:] + lin_b[o]
  gemm_split<<<dim3(64 * 16), dim3(256), 0, stream>>>(
      H1h, H1l, 1024, WLh, WLl, 1024, 1024,
      nullptr, nullptr, 0, out, lin_b, 1, 16);
}

// Round 3
// 9611.409 us; speedup vs baseline: 4.7559x; 4.7559x over previous
//
#include <hip/hip_runtime.h>
#include <math.h>

// ---------------------------------------------------------------------------
// Seq2Seq LSTM (S=128,B=64,I=H=O=1024,L=2,T=64) on gfx950.
// Round 3: no cross-block communication. Weight rows permuted so one 16-row
// MFMA N-tile = all 4 gates of 4 h-cols:
//   perm(gate*1024+hc) = (hc>>2)*16 + (hc&3)*4 + gate
// Stage kernel: 256 blocks (1 col-tile of 4 h-cols each) x 512 thr.
//   8 waves = 2 ops (x-side, h-side) x 4 K-slices(256). acc 4 M-tiles.
//   34KB LDS 8-slice reduce -> fused cell for the block's 4 h-cols.
// No atomics/fences (round-2 regression root cause: per-block device fences).
// ---------------------------------------------------------------------------

typedef unsigned short u16;
typedef short short8 __attribute__((ext_vector_type(8)));
typedef float f32x4 __attribute__((ext_vector_type(4)));

#define MFMA_BF16 __builtin_amdgcn_mfma_f32_16x16x32_bf16

__device__ __forceinline__ u16 f2bf(float x) {
  unsigned u = __builtin_bit_cast(unsigned, x);
  unsigned r = u + 0x7fffu + ((u >> 16) & 1u);   // RNE (no NaN inputs here)
  return (u16)(r >> 16);
}
__device__ __forceinline__ float bf2f(u16 b) {
  return __builtin_bit_cast(float, ((unsigned)b) << 16);
}
__device__ __forceinline__ int permrow(int r) {   // r in [0,4096)
  int gate = r >> 10, hc = r & 1023;
  return ((hc >> 2) << 4) + ((hc & 3) << 2) + gate;
}

// ---------------- prep kernels ----------------

// mode 0: plain; mode 1: transpose (1024x1024); mode 2: permute 4096 rows
__global__ void split_mat(const float* __restrict__ src, u16* __restrict__ dh,
                          u16* __restrict__ dl, int n, int mode) {
  int i = blockIdx.x * 256 + threadIdx.x;
  if (i >= n) return;
  float v = src[i];
  u16 hi = f2bf(v);
  u16 lo = f2bf(v - bf2f(hi));
  int r = i >> 10, c = i & 1023;
  int idx = i;
  if (mode == 1) idx = c * 1024 + r;
  else if (mode == 2) idx = permrow(r) * 1024 + c;
  dh[idx] = hi; dl[idx] = lo;
}

__global__ void zero_f4(float4* __restrict__ p, int n) {
  int i = blockIdx.x * 256 + threadIdx.x;
  if (i < n) p[i] = make_float4(0.f, 0.f, 0.f, 0.f);
}

__global__ void bias_perm(const float* __restrict__ in, float* __restrict__ out) {
  int i = blockIdx.x * 256 + threadIdx.x;
  if (i < 4096) out[permrow(i)] = in[i];
}

// bcomb[perm(n)] = dec_b0[n] + sum_k lin_b[k] * dec_wih0[n][k]
__global__ void bias_comb(const float* __restrict__ db0, const float* __restrict__ lb,
                          const float* __restrict__ wih, float* __restrict__ out) {
  __shared__ float red[256];
  int n = blockIdx.x;
  float s = 0.f;
  for (int k = threadIdx.x; k < 1024; k += 256) s += lb[k] * wih[(size_t)n * 1024 + k];
  red[threadIdx.x] = s;
  __syncthreads();
  for (int d = 128; d > 0; d >>= 1) {
    if (threadIdx.x < d) red[threadIdx.x] += red[threadIdx.x + d];
    __syncthreads();
  }
  if (threadIdx.x == 0) out[permrow(n)] = db0[n] + red[0];
}

// ---------------- generic split-bf16 GEMM: C[M,N] = A[M,K] * B[N,K]^T ------
// mode 0: write split bf16 (hi/lo) to Ch/Cl (Wcomb build; rows inherit A's order)
// mode 1: write fp32 + bias to outp with row=(t*64+b) -> out[b][t][col] scatter
__global__ __launch_bounds__(256) void gemm_split(
    const u16* __restrict__ Ah, const u16* __restrict__ Al, int lda,
    const u16* __restrict__ Bh, const u16* __restrict__ Bl, int ldb,
    int K, u16* __restrict__ Ch, u16* __restrict__ Cl, int ldc,
    float* __restrict__ outp, const float* __restrict__ bias, int mode, int gn) {
  int bm = blockIdx.x / gn, bn = blockIdx.x % gn;
  int l = threadIdx.x & 63, w = threadIdx.x >> 6;
  int n0 = bn * 64 + w * 16;
  int rr = l & 15, ko = (l >> 4) << 3;
  int nrow = n0 + rr;
  f32x4 acc[4] = {};
  for (int kk = 0; kk < K; kk += 32) {
    short8 bh = *(const short8*)(Bh + (size_t)nrow * ldb + kk + ko);
    short8 bl = *(const short8*)(Bl + (size_t)nrow * ldb + kk + ko);
#pragma unroll
    for (int mt = 0; mt < 4; ++mt) {
      size_t ao = (size_t)(bm * 64 + mt * 16 + rr) * lda + kk + ko;
      short8 ah = *(const short8*)(Ah + ao);
      short8 al = *(const short8*)(Al + ao);
      acc[mt] = MFMA_BF16(ah, bh, acc[mt], 0, 0, 0);
      acc[mt] = MFMA_BF16(ah, bl, acc[mt], 0, 0, 0);
      acc[mt] = MFMA_BF16(al, bh, acc[mt], 0, 0, 0);
    }
  }
  int q = l >> 4;
#pragma unroll
  for (int mt = 0; mt < 4; ++mt)
#pragma unroll
    for (int r = 0; r < 4; ++r) {
      int row = bm * 64 + mt * 16 + q * 4 + r;
      int col = n0 + rr;
      float v = acc[mt][r];
      if (mode == 0) {
        u16 hh = f2bf(v);
        Ch[(size_t)row * ldc + col] = hh;
        Cl[(size_t)row * ldc + col] = f2bf(v - bf2f(hh));
      } else {
        int t = row >> 6, b = row & 63;
        outp[(size_t)b * 65536 + t * 1024 + col] = v + bias[col];
      }
    }
}

// ---------------- LSTM stage kernel (self-contained per block) -------------

struct Op { const u16 *Ah, *Al, *Wh, *Wl; };   // W permuted [4096][1024]
struct Stage {
  Op ops[2];           // op0: x-side, op1: h-side
  const float* bias;   // permuted [4096]
  float* c;            // [64][1024] fp32, in-place
  u16 *Hh, *Hl;        // h out (split)
  u16 *Gh, *Gl;        // optional duplicate h dest (H1 history), may be null
  int active;
};

__global__ __launch_bounds__(512, 4) void lstm_stage(Stage s0, Stage s1, int nper) {
  bool first = ((int)blockIdx.x < nper);
  Stage S = first ? s0 : s1;
  if (!S.active) return;
  int j4 = first ? blockIdx.x : (blockIdx.x - nper);   // h-cols 4*j4..4*j4+3
  int tid = threadIdx.x;
  int l = tid & 63, w = tid >> 6;
  int rr = l & 15, ko = (l >> 4) << 3, q = l >> 4;
  Op op = S.ops[w >> 2];
  int kw = (w & 3) << 8;                                // 256-wide K slice
  const u16* __restrict__ Wh = op.Wh + (size_t)((j4 << 4) + rr) * 1024 + kw + ko;
  const u16* __restrict__ Wl = op.Wl + (size_t)((j4 << 4) + rr) * 1024 + kw + ko;
  const u16* __restrict__ Ah = op.Ah + kw + ko;
  const u16* __restrict__ Al = op.Al + kw + ko;

  f32x4 acc[4] = {};
#pragma unroll 2
  for (int it = 0; it < 8; ++it) {
    int kk = it * 32;
    short8 bh = *(const short8*)(Wh + kk);
    short8 bl = *(const short8*)(Wl + kk);
#pragma unroll
    for (int mt = 0; mt < 4; ++mt) {
      size_t ao = (size_t)((mt << 4) + rr) * 1024 + kk;
      short8 ah = *(const short8*)(Ah + ao);
      short8 al = *(const short8*)(Al + ao);
      acc[mt] = MFMA_BF16(ah, bh, acc[mt], 0, 0, 0);
      acc[mt] = MFMA_BF16(ah, bl, acc[mt], 0, 0, 0);
      acc[mt] = MFMA_BF16(al, bh, acc[mt], 0, 0, 0);
    }
  }

  __shared__ float lds[8][64][17];   // 34.8 KB
#pragma unroll
  for (int mt = 0; mt < 4; ++mt)
#pragma unroll
    for (int r = 0; r < 4; ++r)
      lds[w][(mt << 4) + (q << 2) + r][rr] = acc[mt][r];
  __syncthreads();

  if (tid < 256) {
    int b = tid >> 2, sub = tid & 3;
    float g[4];
#pragma unroll
    for (int gt = 0; gt < 4; ++gt) {
      float s = S.bias[(j4 << 4) + (sub << 2) + gt];
#pragma unroll
      for (int ww = 0; ww < 8; ++ww) s += lds[ww][b][(sub << 2) + gt];
      g[gt] = s;
    }
    int col = (j4 << 2) + sub;
    size_t ci = (size_t)b * 1024 + col;
    float cold = S.c[ci];
    float is = 1.f / (1.f + expf(-g[0]));
    float fs = 1.f / (1.f + expf(-g[1]));
    float gg = tanhf(g[2]);
    float os = 1.f / (1.f + expf(-g[3]));
    float cn = fs * cold + is * gg;
    S.c[ci] = cn;
    float h = os * tanhf(cn);
    u16 hh = f2bf(h);
    u16 hl = f2bf(h - bf2f(hh));
    S.Hh[ci] = hh; S.Hl[ci] = hl;
    if (S.Gh) { S.Gh[ci] = hh; S.Gl[ci] = hl; }
  }
}

// ---------------- host ----------------

static inline Stage mkStage(const u16* a0h, const u16* a0l, const u16* w0h, const u16* w0l,
                            const u16* a1h, const u16* a1l, const u16* w1h, const u16* w1l,
                            const float* bias, float* c, u16* Hh, u16* Hl,
                            u16* Gh, u16* Gl, int act) {
  Stage s;
  s.ops[0] = {a0h, a0l, w0h, w0l};
  s.ops[1] = {a1h, a1l, w1h, w1l};
  s.bias = bias; s.c = c; s.Hh = Hh; s.Hl = Hl; s.Gh = Gh; s.Gl = Gl; s.active = act;
  return s;
}

extern "C" void kernel_launch(void* const* d_in, const int* in_sizes, int n_in,
                              void* d_out, int out_size, void* d_ws, size_t ws_size,
                              hipStream_t stream) {
  (void)in_sizes; (void)n_in; (void)out_size; (void)ws_size;
  const float* input_seq = (const float*)d_in[0];   // [128,64,1024]
  const float* enc_wih   = (const float*)d_in[1];   // [2,4096,1024]
  const float* enc_whh   = (const float*)d_in[2];
  const float* enc_b     = (const float*)d_in[3];   // [2,4096]
  const float* dec_wih   = (const float*)d_in[4];
  const float* dec_whh   = (const float*)d_in[5];
  const float* dec_b     = (const float*)d_in[6];
  const float* lin_w     = (const float*)d_in[7];   // [1024,1024]
  const float* lin_b     = (const float*)d_in[8];   // [1024]
  float* out = (float*)d_out;                       // [64,64,1024]

  const size_t WE = 4096ull * 1024;
  const size_t HB = 64ull * 1024;
  char* ws = (char*)d_ws;
  size_t off = 0;
  auto alloc16 = [&](size_t elems) {
    u16* p = (u16*)(ws + off);
    off = (off + elems * 2 + 255) & ~(size_t)255;
    return p;
  };
  auto allocf = [&](size_t elems) {
    float* p = (float*)(ws + off);
    off = (off + elems * 4 + 255) & ~(size_t)255;
    return p;
  };

  // weight splits: stage-kernel weights stored row-PERMUTED
  u16 *WihE0h = alloc16(WE), *WihE0l = alloc16(WE);
  u16 *WhhE0h = alloc16(WE), *WhhE0l = alloc16(WE);
  u16 *WihE1h = alloc16(WE), *WihE1l = alloc16(WE);
  u16 *WhhE1h = alloc16(WE), *WhhE1l = alloc16(WE);
  u16 *WihD0h = alloc16(WE), *WihD0l = alloc16(WE);   // permuted
  u16 *WhhD0h = alloc16(WE), *WhhD0l = alloc16(WE);
  u16 *WihD1h = alloc16(WE), *WihD1l = alloc16(WE);
  u16 *WhhD1h = alloc16(WE), *WhhD1l = alloc16(WE);
  u16 *Wcombh = alloc16(WE), *Wcombl = alloc16(WE);   // inherits perm from WihD0
  u16 *WLh  = alloc16(1024 * 1024), *WLl  = alloc16(1024 * 1024);   // lin_w
  u16 *WLTh = alloc16(1024 * 1024), *WLTl = alloc16(1024 * 1024);   // lin_w^T
  u16 *XSh = alloc16(8192ull * 1024), *XSl = alloc16(8192ull * 1024);
  u16 *H1h = alloc16(64 * HB), *H1l = alloc16(64 * HB);
  // zeroed state region
  size_t zbeg = off;
  u16 *h0h = alloc16(2 * HB), *h0l = alloc16(2 * HB);
  u16 *h1h = alloc16(2 * HB), *h1l = alloc16(2 * HB);
  float *c0 = allocf(HB), *c1 = allocf(HB);
  size_t zend = off;
  // permuted biases
  float *ebp0 = allocf(4096), *ebp1 = allocf(4096);
  float *dbp0 = allocf(4096), *dbp1 = allocf(4096);
  float *bdec0 = allocf(4096);

  // 1) zero state region
  {
    int n4 = (int)((zend - zbeg) / 16);
    zero_f4<<<dim3((n4 + 255) / 256), dim3(256), 0, stream>>>((float4*)(ws + zbeg), n4);
  }
  // 2) split inputs & weights (weights mode 2 = row-permuted)
  auto split = [&](const float* src, u16* dh, u16* dl, int n, int mode) {
    split_mat<<<dim3((n + 255) / 256), dim3(256), 0, stream>>>(src, dh, dl, n, mode);
  };
  split(input_seq, XSh, XSl, 8192 * 1024, 0);
  split(enc_wih,        WihE0h, WihE0l, (int)WE, 2);
  split(enc_whh,        WhhE0h, WhhE0l, (int)WE, 2);
  split(enc_wih + WE,   WihE1h, WihE1l, (int)WE, 2);
  split(enc_whh + WE,   WhhE1h, WhhE1l, (int)WE, 2);
  split(dec_wih,        WihD0h, WihD0l, (int)WE, 2);
  split(dec_whh,        WhhD0h, WhhD0l, (int)WE, 2);
  split(dec_wih + WE,   WihD1h, WihD1l, (int)WE, 2);
  split(dec_whh + WE,   WhhD1h, WhhD1l, (int)WE, 2);
  split(lin_w, WLh,  WLl,  1024 * 1024, 0);
  split(lin_w, WLTh, WLTl, 1024 * 1024, 1);
  // 3) permuted biases
  bias_perm<<<dim3(16), dim3(256), 0, stream>>>(enc_b,        ebp0);
  bias_perm<<<dim3(16), dim3(256), 0, stream>>>(enc_b + 4096, ebp1);
  bias_perm<<<dim3(16), dim3(256), 0, stream>>>(dec_b,        dbp0);
  bias_perm<<<dim3(16), dim3(256), 0, stream>>>(dec_b + 4096, dbp1);
  bias_comb<<<dim3(4096), dim3(256), 0, stream>>>(dec_b, lin_b, dec_wih, bdec0);
  // 4) Wcomb[perm-rows][h] = WihD0perm @ lin_w  (A already permuted)
  gemm_split<<<dim3(64 * 16), dim3(256), 0, stream>>>(
      WihD0h, WihD0l, 1024, WLTh, WLTl, 1024, 1024,
      Wcombh, Wcombl, 1024, nullptr, nullptr, 0, 16);

  // 5) encoder: pipelined L0(s) + L1(s-1), s = 0..128; 512 blocks/launch
  for (int s = 0; s <= 128; ++s) {
    int u = s - 1;
    Stage L0 = mkStage(
        XSh + (size_t)s * HB, XSl + (size_t)s * HB, WihE0h, WihE0l,
        h0h + ((s + 1) & 1) * HB, h0l + ((s + 1) & 1) * HB, WhhE0h, WhhE0l,
        ebp0, c0, h0h + (s & 1) * HB, h0l + (s & 1) * HB,
        nullptr, nullptr, s < 128 ? 1 : 0);
    Stage L1 = mkStage(
        h0h + (u & 1) * HB, h0l + (u & 1) * HB, WihE1h, WihE1l,
        h1h + ((u + 1) & 1) * HB, h1l + ((u + 1) & 1) * HB, WhhE1h, WhhE1l,
        ebp1, c1, h1h + (u & 1) * HB, h1l + (u & 1) * HB,
        nullptr, nullptr, s >= 1 ? 1 : 0);
    lstm_stage<<<dim3(512), dim3(512), 0, stream>>>(L0, L1, 256);
  }

  // 6) decoder: per step, stage A (L0, head folded) then stage B (L1)
  for (int t = 0; t < 64; ++t) {
    Stage A;
    if (t == 0) {
      A = mkStage(XSh + 127ull * HB, XSl + 127ull * HB, WihD0h, WihD0l,
                  h0h + ((t + 1) & 1) * HB, h0l + ((t + 1) & 1) * HB, WhhD0h, WhhD0l,
                  dbp0, c0, h0h + (t & 1) * HB, h0l + (t & 1) * HB,
                  nullptr, nullptr, 1);
    } else {
      A = mkStage(h1h + ((t - 1) & 1) * HB, h1l + ((t - 1) & 1) * HB, Wcombh, Wcombl,
                  h0h + ((t + 1) & 1) * HB, h0l + ((t + 1) & 1) * HB, WhhD0h, WhhD0l,
                  bdec0, c0, h0h + (t & 1) * HB, h0l + (t & 1) * HB,
                  nullptr, nullptr, 1);
    }
    lstm_stage<<<dim3(256), dim3(512), 0, stream>>>(A, A, 256);
    Stage Bst = mkStage(
        h0h + (t & 1) * HB, h0l + (t & 1) * HB, WihD1h, WihD1l,
        h1h + ((t + 1) & 1) * HB, h1l + ((t + 1) & 1) * HB, WhhD1h, WhhD1l,
        dbp1, c1, h1h + (t & 1) * HB, h1l + (t & 1) * HB,
        H1h + (size_t)t * HB, H1l + (size_t)t * HB, 1);
    lstm_stage<<<dim3(256), dim3(512), 0, stream>>>(Bst, Bst, 256);
  }

  // 7) y[b][t][o] = H1[t*64+b][:] . lin_w[o][:] + lin_b[o]
  gemm_split<<<dim3(64 * 16), dim3(256), 0, stream>>>(
      H1h, H1l, 1024, WLh, WLl, 1024, 1024,
      nullptr, nullptr, 0, out, lin_b, 1, 16);
}

// Round 5
// 9202.283 us; speedup vs baseline: 4.9673x; 1.0445x over previous
//
#include <hip/hip_runtime.h>
#include <math.h>

// ---------------------------------------------------------------------------
// Seq2Seq LSTM (S=128,B=64,I=H=O=1024,L=2,T=64) on gfx950.
// Round 5: Round-4 structure, workspace shrunk to ~204 MB (round-4 core dump
// = d_ws overrun at ~268 MB; 256 MB limit inferred from rounds 2-4).
//  - X split per 16-step chunk (4 MB ping) instead of full 32 MB split.
//  - H0 sequence -> 17-slot chunk ring; L0/L1 interleave chunk-wise; carry
//    via dup-dest write of the step kernel.
//  - One 16 MB fp32 G buffer reused for L0/L1 gate preloads per chunk.
//  - gemm_split: 2 N-tiles/wave (24 MFMA : 12 loads) for hoisted GEMMs.
//  - Weight rows permuted: perm(gate*1024+hc) = (hc>>2)*16 + (hc&3)*4 + gate.
//  - Decoder: head folded into L0 (Wcomb); per-step 2 stages of 2 ops.
// ---------------------------------------------------------------------------

typedef unsigned short u16;
typedef short short8 __attribute__((ext_vector_type(8)));
typedef float f32x4 __attribute__((ext_vector_type(4)));

#define MFMA_BF16 __builtin_amdgcn_mfma_f32_16x16x32_bf16

__device__ __forceinline__ u16 f2bf(float x) {
  unsigned u = __builtin_bit_cast(unsigned, x);
  unsigned r = u + 0x7fffu + ((u >> 16) & 1u);
  return (u16)(r >> 16);
}
__device__ __forceinline__ float bf2f(u16 b) {
  return __builtin_bit_cast(float, ((unsigned)b) << 16);
}
__device__ __forceinline__ int permrow(int r) {
  int gate = r >> 10, hc = r & 1023;
  return ((hc >> 2) << 4) + ((hc & 3) << 2) + gate;
}

// ---------------- prep kernels ----------------

// mode 0: plain; mode 1: transpose (1024x1024); mode 2: permute 4096 rows
__global__ void split_mat(const float* __restrict__ src, u16* __restrict__ dh,
                          u16* __restrict__ dl, int n, int mode) {
  int i = blockIdx.x * 256 + threadIdx.x;
  if (i >= n) return;
  float v = src[i];
  u16 hi = f2bf(v);
  u16 lo = f2bf(v - bf2f(hi));
  int r = i >> 10, c = i & 1023;
  int idx = i;
  if (mode == 1) idx = c * 1024 + r;
  else if (mode == 2) idx = permrow(r) * 1024 + c;
  dh[idx] = hi; dl[idx] = lo;
}

__global__ void zero_f4(float4* __restrict__ p, int n) {
  int i = blockIdx.x * 256 + threadIdx.x;
  if (i < n) p[i] = make_float4(0.f, 0.f, 0.f, 0.f);
}

__global__ void bias_perm(const float* __restrict__ in, float* __restrict__ out) {
  int i = blockIdx.x * 256 + threadIdx.x;
  if (i < 4096) out[permrow(i)] = in[i];
}

// bcomb[perm(n)] = dec_b0[n] + sum_k lin_b[k] * dec_wih0[n][k]
__global__ void bias_comb(const float* __restrict__ db0, const float* __restrict__ lb,
                          const float* __restrict__ wih, float* __restrict__ out) {
  __shared__ float red[256];
  int n = blockIdx.x;
  float s = 0.f;
  for (int k = threadIdx.x; k < 1024; k += 256) s += lb[k] * wih[(size_t)n * 1024 + k];
  red[threadIdx.x] = s;
  __syncthreads();
  for (int d = 128; d > 0; d >>= 1) {
    if (threadIdx.x < d) red[threadIdx.x] += red[threadIdx.x + d];
    __syncthreads();
  }
  if (threadIdx.x == 0) out[permrow(n)] = db0[n] + red[0];
}

// ---------- split-bf16 GEMM: C[M,N] = A[M,K] * B[N,K]^T ----------
// Block: 64 M-rows x 128 N-cols; 4 waves x (2 N-tiles/wave). gn = N/128.
// mode 0: split-bf16 C; mode 1: fp32+bias, row=(t*64+b)->out[b][t][col];
// mode 2: plain fp32 C.
__global__ __launch_bounds__(256) void gemm_split(
    const u16* __restrict__ Ah, const u16* __restrict__ Al, int lda,
    const u16* __restrict__ Bh, const u16* __restrict__ Bl, int ldb,
    int K, int gn,
    u16* __restrict__ Ch, u16* __restrict__ Cl, int ldc,
    float* __restrict__ outp, const float* __restrict__ bias, int ldout, int mode) {
  int bm = blockIdx.x / gn, bn = blockIdx.x % gn;
  int l = threadIdx.x & 63, w = threadIdx.x >> 6;
  int n0 = bn * 128 + w * 32;
  int rr = l & 15, ko = (l >> 4) << 3, q = l >> 4;
  int M0 = bm * 64;
  f32x4 acc[8] = {};
  for (int kk = 0; kk < K; kk += 32) {
    short8 bh[2], bl[2];
#pragma unroll
    for (int nt = 0; nt < 2; ++nt) {
      size_t bo = (size_t)(n0 + nt * 16 + rr) * ldb + kk + ko;
      bh[nt] = *(const short8*)(Bh + bo);
      bl[nt] = *(const short8*)(Bl + bo);
    }
#pragma unroll
    for (int mt = 0; mt < 4; ++mt) {
      size_t ao = (size_t)(M0 + mt * 16 + rr) * lda + kk + ko;
      short8 ah = *(const short8*)(Ah + ao);
      short8 al = *(const short8*)(Al + ao);
#pragma unroll
      for (int nt = 0; nt < 2; ++nt) {
        f32x4 t = acc[mt * 2 + nt];
        t = MFMA_BF16(ah, bh[nt], t, 0, 0, 0);
        t = MFMA_BF16(ah, bl[nt], t, 0, 0, 0);
        t = MFMA_BF16(al, bh[nt], t, 0, 0, 0);
        acc[mt * 2 + nt] = t;
      }
    }
  }
#pragma unroll
  for (int mt = 0; mt < 4; ++mt)
#pragma unroll
    for (int nt = 0; nt < 2; ++nt)
#pragma unroll
      for (int r = 0; r < 4; ++r) {
        int row = M0 + mt * 16 + q * 4 + r;
        int col = n0 + nt * 16 + rr;
        float v = acc[mt * 2 + nt][r];
        if (mode == 0) {
          u16 hh = f2bf(v);
          Ch[(size_t)row * ldc + col] = hh;
          Cl[(size_t)row * ldc + col] = f2bf(v - bf2f(hh));
        } else if (mode == 1) {
          int t = row >> 6, b = row & 63;
          outp[(size_t)b * 65536 + t * 1024 + col] = v + bias[col];
        } else {
          outp[(size_t)row * ldout + col] = v;
        }
      }
}

// ---------------- recurrent LSTM step kernel ----------------
// 128 blocks; block -> 32 perm-rows (8 h-cols), XCD-pinned mapping.
// 8 waves = nops x (8/nops) K-slices; wave: M=64 x N=32.

struct Op { const u16 *Ah, *Al, *Wh, *Wl; };
struct Stage {
  Op ops[2];
  int nops;            // 1 or 2
  const float* pre;    // optional fp32 [64][4096] gate preload
  const float* bias;   // permuted [4096]
  float* c;            // [64][1024] fp32 in-place
  u16 *Hh, *Hl;        // h out (split)
  u16 *Gh, *Gl;        // optional duplicate h dest (carry / history)
};

__global__ __launch_bounds__(512, 2) void lstm_step(Stage S) {
  int j = blockIdx.x;
  int rowblk = ((j & 7) << 4) + (j >> 3);     // XCD-pinned mapping
  int R = rowblk << 5;                         // 32 perm-rows
  int tid = threadIdx.x;
  int l = tid & 63, w = tid >> 6;
  int rr = l & 15, ko = (l >> 4) << 3, q = l >> 4;
  int kslices = 8 / S.nops;
  int kwidth = 1024 / kslices;                 // 128 or 256
  Op op = S.ops[w / kslices];
  int kb = (w % kslices) * kwidth;
  const u16* __restrict__ Wh = op.Wh + (size_t)(R + rr) * 1024 + kb + ko;
  const u16* __restrict__ Wl = op.Wl + (size_t)(R + rr) * 1024 + kb + ko;
  const u16* __restrict__ Ah = op.Ah + kb + ko;
  const u16* __restrict__ Al = op.Al + kb + ko;

  f32x4 acc[8] = {};
#pragma unroll 2
  for (int kk = 0; kk < kwidth; kk += 32) {
    short8 bh[2], bl[2];
#pragma unroll
    for (int nt = 0; nt < 2; ++nt) {
      bh[nt] = *(const short8*)(Wh + (size_t)(nt << 4) * 1024 + kk);
      bl[nt] = *(const short8*)(Wl + (size_t)(nt << 4) * 1024 + kk);
    }
#pragma unroll
    for (int mt = 0; mt < 4; ++mt) {
      size_t ao = (size_t)((mt << 4) + rr) * 1024 + kk;
      short8 ah = *(const short8*)(Ah + ao);
      short8 al = *(const short8*)(Al + ao);
#pragma unroll
      for (int nt = 0; nt < 2; ++nt) {
        f32x4 t = acc[mt * 2 + nt];
        t = MFMA_BF16(ah, bh[nt], t, 0, 0, 0);
        t = MFMA_BF16(ah, bl[nt], t, 0, 0, 0);
        t = MFMA_BF16(al, bh[nt], t, 0, 0, 0);
        acc[mt * 2 + nt] = t;
      }
    }
  }

  __shared__ float lds[8][64][33];             // 67.6 KB
#pragma unroll
  for (int mt = 0; mt < 4; ++mt)
#pragma unroll
    for (int nt = 0; nt < 2; ++nt)
#pragma unroll
      for (int r = 0; r < 4; ++r)
        lds[w][(mt << 4) + (q << 2) + r][(nt << 4) + rr] = acc[mt * 2 + nt][r];
  __syncthreads();

  int b = tid >> 3, e = tid & 7;
  float g[4];
#pragma unroll
  for (int gt = 0; gt < 4; ++gt) {
    int c = (e << 2) + gt;
    float s = S.bias[R + c];
    if (S.pre) s += S.pre[(size_t)b * 4096 + R + c];
#pragma unroll
    for (int ww = 0; ww < 8; ++ww) s += lds[ww][b][c];
    g[gt] = s;
  }
  int hc = (rowblk << 3) + ((e >> 2) << 2) + (e & 3);
  size_t ci = (size_t)b * 1024 + hc;
  float cold = S.c[ci];
  float is = 1.f / (1.f + expf(-g[0]));
  float fs = 1.f / (1.f + expf(-g[1]));
  float gg = tanhf(g[2]);
  float os = 1.f / (1.f + expf(-g[3]));
  float cn = fs * cold + is * gg;
  S.c[ci] = cn;
  float h = os * tanhf(cn);
  u16 hh = f2bf(h);
  u16 hl = f2bf(h - bf2f(hh));
  S.Hh[ci] = hh; S.Hl[ci] = hl;
  if (S.Gh) { S.Gh[ci] = hh; S.Gl[ci] = hl; }
}

// ---------------- host ----------------

static inline Stage mk1(const u16* ah, const u16* al, const u16* wh, const u16* wl,
                        const float* pre, const float* bias, float* c,
                        u16* Hh, u16* Hl, u16* Gh, u16* Gl) {
  Stage s;
  s.ops[0] = {ah, al, wh, wl};
  s.ops[1] = {ah, al, wh, wl};
  s.nops = 1; s.pre = pre; s.bias = bias; s.c = c;
  s.Hh = Hh; s.Hl = Hl; s.Gh = Gh; s.Gl = Gl;
  return s;
}
static inline Stage mk2(const u16* a0h, const u16* a0l, const u16* w0h, const u16* w0l,
                        const u16* a1h, const u16* a1l, const u16* w1h, const u16* w1l,
                        const float* bias, float* c,
                        u16* Hh, u16* Hl, u16* Gh, u16* Gl) {
  Stage s;
  s.ops[0] = {a0h, a0l, w0h, w0l};
  s.ops[1] = {a1h, a1l, w1h, w1l};
  s.nops = 2; s.pre = nullptr; s.bias = bias; s.c = c;
  s.Hh = Hh; s.Hl = Hl; s.Gh = Gh; s.Gl = Gl;
  return s;
}

extern "C" void kernel_launch(void* const* d_in, const int* in_sizes, int n_in,
                              void* d_out, int out_size, void* d_ws, size_t ws_size,
                              hipStream_t stream) {
  (void)in_sizes; (void)n_in; (void)out_size; (void)ws_size;
  const float* input_seq = (const float*)d_in[0];
  const float* enc_wih   = (const float*)d_in[1];
  const float* enc_whh   = (const float*)d_in[2];
  const float* enc_b     = (const float*)d_in[3];
  const float* dec_wih   = (const float*)d_in[4];
  const float* dec_whh   = (const float*)d_in[5];
  const float* dec_b     = (const float*)d_in[6];
  const float* lin_w     = (const float*)d_in[7];
  const float* lin_b     = (const float*)d_in[8];
  float* out = (float*)d_out;

  const size_t WE = 4096ull * 1024;
  const size_t HB = 64ull * 1024;           // one [64][1024] slab (elements)
  char* ws = (char*)d_ws;
  size_t off = 0;
  auto alloc16 = [&](size_t elems) {
    u16* p = (u16*)(ws + off);
    off = (off + elems * 2 + 255) & ~(size_t)255;
    return p;
  };
  auto allocf = [&](size_t elems) {
    float* p = (float*)(ws + off);
    off = (off + elems * 4 + 255) & ~(size_t)255;
    return p;
  };

  // weights (permuted rows) split hi/lo: 18 x 8 MB = 144 MB
  u16 *WihE0h = alloc16(WE), *WihE0l = alloc16(WE);
  u16 *WhhE0h = alloc16(WE), *WhhE0l = alloc16(WE);
  u16 *WihE1h = alloc16(WE), *WihE1l = alloc16(WE);
  u16 *WhhE1h = alloc16(WE), *WhhE1l = alloc16(WE);
  u16 *WihD0h = alloc16(WE), *WihD0l = alloc16(WE);
  u16 *WhhD0h = alloc16(WE), *WhhD0l = alloc16(WE);
  u16 *WihD1h = alloc16(WE), *WihD1l = alloc16(WE);
  u16 *WhhD1h = alloc16(WE), *WhhD1l = alloc16(WE);
  u16 *Wcombh = alloc16(WE), *Wcombl = alloc16(WE);
  u16 *WLh  = alloc16(1024 * 1024), *WLl  = alloc16(1024 * 1024);  // 8 MB tot
  u16 *WLTh = alloc16(1024 * 1024), *WLTl = alloc16(1024 * 1024);
  u16 *XCh = alloc16(16 * HB), *XCl = alloc16(16 * HB);            // 4 MB chunk
  u16 *XLh = alloc16(HB), *XLl = alloc16(HB);                      // x_last
  u16 *H0ch = alloc16(17 * HB), *H0cl = alloc16(17 * HB);          // 4.5 MB ring
  u16 *H1h = alloc16(64 * HB), *H1l = alloc16(64 * HB);            // 16 MB
  // zero region: zh/zl (zero h), c0, c1
  size_t zbeg = off;
  u16 *zh = alloc16(HB), *zl = alloc16(HB);
  float *c0 = allocf(HB), *c1 = allocf(HB);
  size_t zend = off;
  // ping-pong h slots
  u16 *e1h = alloc16(2 * HB), *e1l = alloc16(2 * HB);
  u16 *d0h = alloc16(2 * HB), *d0l = alloc16(2 * HB);
  u16 *d1h = alloc16(2 * HB), *d1l = alloc16(2 * HB);
  // gate buffers
  float *G   = allocf(1024ull * 4096);      // 16 MB (16-step chunk)
  float *Gd0 = allocf(64 * 4096);           // 1 MB
  // biases
  float *ebp0 = allocf(4096), *ebp1 = allocf(4096);
  float *dbp0 = allocf(4096), *dbp1 = allocf(4096);
  float *bdec0 = allocf(4096);
  // total ~204 MB

  // 1) zeros
  {
    int n4 = (int)((zend - zbeg) / 16);
    zero_f4<<<dim3((n4 + 255) / 256), dim3(256), 0, stream>>>((float4*)(ws + zbeg), n4);
  }
  // 2) weight / small splits
  auto split = [&](const float* src, u16* dh, u16* dl, int n, int mode) {
    split_mat<<<dim3((n + 255) / 256), dim3(256), 0, stream>>>(src, dh, dl, n, mode);
  };
  split(enc_wih,        WihE0h, WihE0l, (int)WE, 2);
  split(enc_whh,        WhhE0h, WhhE0l, (int)WE, 2);
  split(enc_wih + WE,   WihE1h, WihE1l, (int)WE, 2);
  split(enc_whh + WE,   WhhE1h, WhhE1l, (int)WE, 2);
  split(dec_wih,        WihD0h, WihD0l, (int)WE, 2);
  split(dec_whh,        WhhD0h, WhhD0l, (int)WE, 2);
  split(dec_wih + WE,   WihD1h, WihD1l, (int)WE, 2);
  split(dec_whh + WE,   WhhD1h, WhhD1l, (int)WE, 2);
  split(lin_w, WLh,  WLl,  1024 * 1024, 0);
  split(lin_w, WLTh, WLTl, 1024 * 1024, 1);
  split(input_seq + 127ull * HB, XLh, XLl, (int)HB, 0);
  // 3) biases
  bias_perm<<<dim3(16), dim3(256), 0, stream>>>(enc_b,        ebp0);
  bias_perm<<<dim3(16), dim3(256), 0, stream>>>(enc_b + 4096, ebp1);
  bias_perm<<<dim3(16), dim3(256), 0, stream>>>(dec_b,        dbp0);
  bias_perm<<<dim3(16), dim3(256), 0, stream>>>(dec_b + 4096, dbp1);
  bias_comb<<<dim3(4096), dim3(256), 0, stream>>>(dec_b, lin_b, dec_wih, bdec0);
  // 4) Wcomb = WihD0(perm) @ lin_w : M=4096,N=1024,K=1024 -> grid 64*8
  gemm_split<<<dim3(64 * 8), dim3(256), 0, stream>>>(
      WihD0h, WihD0l, 1024, WLTh, WLTl, 1024, 1024, 8,
      Wcombh, Wcombl, 1024, nullptr, nullptr, 0, 0);
  // 4b) Gd0 = x_last @ WihD0^T : M=64,N=4096 -> grid 1*32
  gemm_split<<<dim3(32), dim3(256), 0, stream>>>(
      XLh, XLl, 1024, WihD0h, WihD0l, 1024, 1024, 32,
      nullptr, nullptr, 0, Gd0, nullptr, 4096, 2);

  // 5) encoder: 8 chunks x (split XC, G0 gemm, 16 L0 steps, G1 gemm, 16 L1)
  for (int ch = 0; ch < 8; ++ch) {
    split(input_seq + (size_t)ch * 16 * HB, XCh, XCl, (int)(16 * HB), 0);
    // G0[lt*64+b][n] = XC @ WihE0^T : M=1024,N=4096 -> grid 16*32
    gemm_split<<<dim3(16 * 32), dim3(256), 0, stream>>>(
        XCh, XCl, 1024, WihE0h, WihE0l, 1024, 1024, 32,
        nullptr, nullptr, 0, G, nullptr, 4096, 2);
    for (int lt = 0; lt < 16; ++lt) {
      bool g0 = (ch == 0 && lt == 0);
      const u16* hin_h = g0 ? zh : H0ch + (size_t)lt * HB;
      const u16* hin_l = g0 ? zl : H0cl + (size_t)lt * HB;
      Stage S = mk1(hin_h, hin_l, WhhE0h, WhhE0l,
                    G + (size_t)lt * 64 * 4096, ebp0, c0,
                    H0ch + (size_t)(lt + 1) * HB, H0cl + (size_t)(lt + 1) * HB,
                    (lt == 15) ? H0ch : nullptr, (lt == 15) ? H0cl : nullptr);
      lstm_step<<<dim3(128), dim3(512), 0, stream>>>(S);
    }
    // G1[lt*64+b][n] = H0c[1..16] @ WihE1^T
    gemm_split<<<dim3(16 * 32), dim3(256), 0, stream>>>(
        H0ch + HB, H0cl + HB, 1024, WihE1h, WihE1l, 1024, 1024, 32,
        nullptr, nullptr, 0, G, nullptr, 4096, 2);
    for (int lt = 0; lt < 16; ++lt) {
      int t = ch * 16 + lt;
      const u16* hin_h = (t == 0) ? zh : e1h + (size_t)((t - 1) & 1) * HB;
      const u16* hin_l = (t == 0) ? zl : e1l + (size_t)((t - 1) & 1) * HB;
      Stage S = mk1(hin_h, hin_l, WhhE1h, WhhE1l,
                    G + (size_t)lt * 64 * 4096, ebp1, c1,
                    e1h + (size_t)(t & 1) * HB, e1l + (size_t)(t & 1) * HB,
                    nullptr, nullptr);
      lstm_step<<<dim3(128), dim3(512), 0, stream>>>(S);
    }
  }

  // 6) decoder: 64 steps x 2 stages
  for (int t = 0; t < 64; ++t) {
    const u16 *h0p_h = (t == 0) ? H0ch + 16ull * HB : d0h + (size_t)((t - 1) & 1) * HB;
    const u16 *h0p_l = (t == 0) ? H0cl + 16ull * HB : d0l + (size_t)((t - 1) & 1) * HB;
    const u16 *h1p_h = (t == 0) ? e1h + HB : d1h + (size_t)((t - 1) & 1) * HB;
    const u16 *h1p_l = (t == 0) ? e1l + HB : d1l + (size_t)((t - 1) & 1) * HB;
    Stage A;
    if (t == 0) {
      A = mk1(h0p_h, h0p_l, WhhD0h, WhhD0l, Gd0, dbp0, c0,
              d0h, d0l, nullptr, nullptr);
    } else {
      A = mk2(h1p_h, h1p_l, Wcombh, Wcombl, h0p_h, h0p_l, WhhD0h, WhhD0l,
              bdec0, c0,
              d0h + (size_t)(t & 1) * HB, d0l + (size_t)(t & 1) * HB,
              nullptr, nullptr);
    }
    lstm_step<<<dim3(128), dim3(512), 0, stream>>>(A);
    Stage Bst = mk2(d0h + (size_t)(t & 1) * HB, d0l + (size_t)(t & 1) * HB, WihD1h, WihD1l,
                    h1p_h, h1p_l, WhhD1h, WhhD1l,
                    dbp1, c1,
                    d1h + (size_t)(t & 1) * HB, d1l + (size_t)(t & 1) * HB,
                    H1h + (size_t)t * HB, H1l + (size_t)t * HB);
    lstm_step<<<dim3(128), dim3(512), 0, stream>>>(Bst);
  }

  // 7) y[b][t][o] = H1[t*64+b][:] . lin_w[o][:] + lin_b[o] : M=4096,N=1024
  gemm_split<<<dim3(64 * 8), dim3(256), 0, stream>>>(
      H1h, H1l, 1024, WLh, WLl, 1024, 1024, 8,
      nullptr, nullptr, 0, out, lin_b, 1024, 1);
}

// Round 6
// 6578.149 us; speedup vs baseline: 6.9489x; 1.3989x over previous
//
#include <hip/hip_runtime.h>
#include <math.h>

// ---------------------------------------------------------------------------
// Seq2Seq LSTM (S=128,B=64,I=H=O=1024,L=2,T=64) on gfx950.
// Round 6: engage all 256 CUs per recurrent stage (R5 steps used 128 blocks
// = per-CU-throughput-bound). Changes:
//  - Decoder: lstm_one, 256 blocks x 16 perm-rows (4 h-cols), 8 waves =
//    nops x K-slices; per-CU bytes ~640KB -> ~half, 2x CUs.
//  - Encoder: lstm_pair, L0(chunk ch) paired with L1(chunk ch-1) in one
//    256-block launch (L1 lags 16 steps; G1 preload from prev chunk).
//    128 paired launches + 16 drain. XCD-pinned rows -> per-XCD W slice
//    2+2 MB, L2-residency bet.
//  - gemm_split<MT>: M-tile 128 for hoisted GEMMs (B-reread halved).
//  - Weight rows permuted: perm(gate*1024+hc) = (hc>>2)*16 + (hc&3)*4 + gate.
//  - Decoder head folded into L0 (Wcomb); split-bf16 (3x MFMA) throughout.
// ---------------------------------------------------------------------------

typedef unsigned short u16;
typedef short short8 __attribute__((ext_vector_type(8)));
typedef float f32x4 __attribute__((ext_vector_type(4)));

#define MFMA_BF16 __builtin_amdgcn_mfma_f32_16x16x32_bf16

__device__ __forceinline__ u16 f2bf(float x) {
  unsigned u = __builtin_bit_cast(unsigned, x);
  unsigned r = u + 0x7fffu + ((u >> 16) & 1u);
  return (u16)(r >> 16);
}
__device__ __forceinline__ float bf2f(u16 b) {
  return __builtin_bit_cast(float, ((unsigned)b) << 16);
}
__device__ __forceinline__ int permrow(int r) {
  int gate = r >> 10, hc = r & 1023;
  return ((hc >> 2) << 4) + ((hc & 3) << 2) + gate;
}

// ---------------- prep kernels ----------------

// mode 0: plain; mode 1: transpose (1024x1024); mode 2: permute 4096 rows
__global__ void split_mat(const float* __restrict__ src, u16* __restrict__ dh,
                          u16* __restrict__ dl, int n, int mode) {
  int i = blockIdx.x * 256 + threadIdx.x;
  if (i >= n) return;
  float v = src[i];
  u16 hi = f2bf(v);
  u16 lo = f2bf(v - bf2f(hi));
  int r = i >> 10, c = i & 1023;
  int idx = i;
  if (mode == 1) idx = c * 1024 + r;
  else if (mode == 2) idx = permrow(r) * 1024 + c;
  dh[idx] = hi; dl[idx] = lo;
}

__global__ void zero_f4(float4* __restrict__ p, int n) {
  int i = blockIdx.x * 256 + threadIdx.x;
  if (i < n) p[i] = make_float4(0.f, 0.f, 0.f, 0.f);
}

__global__ void bias_perm(const float* __restrict__ in, float* __restrict__ out) {
  int i = blockIdx.x * 256 + threadIdx.x;
  if (i < 4096) out[permrow(i)] = in[i];
}

// bcomb[perm(n)] = dec_b0[n] + sum_k lin_b[k] * dec_wih0[n][k]
__global__ void bias_comb(const float* __restrict__ db0, const float* __restrict__ lb,
                          const float* __restrict__ wih, float* __restrict__ out) {
  __shared__ float red[256];
  int n = blockIdx.x;
  float s = 0.f;
  for (int k = threadIdx.x; k < 1024; k += 256) s += lb[k] * wih[(size_t)n * 1024 + k];
  red[threadIdx.x] = s;
  __syncthreads();
  for (int d = 128; d > 0; d >>= 1) {
    if (threadIdx.x < d) red[threadIdx.x] += red[threadIdx.x + d];
    __syncthreads();
  }
  if (threadIdx.x == 0) out[permrow(n)] = db0[n] + red[0];
}

// ---------- split-bf16 GEMM: C[M,N] = A[M,K] * B[N,K]^T ----------
// Block: (64*MT) M-rows x 128 N-cols; 4 waves x 2 N-tiles. gn = N/128.
// mode 0: split-bf16 C; mode 1: fp32+bias, row=(t*64+b)->out[b][t][col];
// mode 2: plain fp32 C.
template<int MT>
__global__ __launch_bounds__(256) void gemm_split(
    const u16* __restrict__ Ah, const u16* __restrict__ Al, int lda,
    const u16* __restrict__ Bh, const u16* __restrict__ Bl, int ldb,
    int K, int gn,
    u16* __restrict__ Ch, u16* __restrict__ Cl, int ldc,
    float* __restrict__ outp, const float* __restrict__ bias, int ldout, int mode) {
  int bm = blockIdx.x / gn, bn = blockIdx.x % gn;
  int l = threadIdx.x & 63, w = threadIdx.x >> 6;
  int n0 = bn * 128 + w * 32;
  int rr = l & 15, ko = (l >> 4) << 3, q = l >> 4;
  int M0 = bm * 64 * MT;
  f32x4 acc[8 * MT] = {};
  for (int kk = 0; kk < K; kk += 32) {
    short8 bh[2], bl[2];
#pragma unroll
    for (int nt = 0; nt < 2; ++nt) {
      size_t bo = (size_t)(n0 + nt * 16 + rr) * ldb + kk + ko;
      bh[nt] = *(const short8*)(Bh + bo);
      bl[nt] = *(const short8*)(Bl + bo);
    }
#pragma unroll
    for (int mt = 0; mt < 4 * MT; ++mt) {
      size_t ao = (size_t)(M0 + mt * 16 + rr) * lda + kk + ko;
      short8 ah = *(const short8*)(Ah + ao);
      short8 al = *(const short8*)(Al + ao);
#pragma unroll
      for (int nt = 0; nt < 2; ++nt) {
        f32x4 t = acc[mt * 2 + nt];
        t = MFMA_BF16(ah, bh[nt], t, 0, 0, 0);
        t = MFMA_BF16(ah, bl[nt], t, 0, 0, 0);
        t = MFMA_BF16(al, bh[nt], t, 0, 0, 0);
        acc[mt * 2 + nt] = t;
      }
    }
  }
#pragma unroll
  for (int mt = 0; mt < 4 * MT; ++mt)
#pragma unroll
    for (int nt = 0; nt < 2; ++nt)
#pragma unroll
      for (int r = 0; r < 4; ++r) {
        int row = M0 + mt * 16 + q * 4 + r;
        int col = n0 + nt * 16 + rr;
        float v = acc[mt * 2 + nt][r];
        if (mode == 0) {
          u16 hh = f2bf(v);
          Ch[(size_t)row * ldc + col] = hh;
          Cl[(size_t)row * ldc + col] = f2bf(v - bf2f(hh));
        } else if (mode == 1) {
          int t = row >> 6, b = row & 63;
          outp[(size_t)b * 65536 + t * 1024 + col] = v + bias[col];
        } else {
          outp[(size_t)row * ldout + col] = v;
        }
      }
}

// ---------------- encoder paired step kernel ----------------
// 256 blocks = 2 halves x 128 blocks; block = 32 perm-rows (8 h-cols).
// Each half is a 1-op h-side step + fp32 gate preload. XCD-pinned rows.

struct Half {
  const u16 *Ah, *Al, *Wh, *Wl;
  const float* pre;    // fp32 [64][4096] gate slab
  const float* bias;   // permuted [4096]
  float* c;
  u16 *Hh, *Hl;
  int active;
};

__global__ __launch_bounds__(512, 1) void lstm_pair(Half hA, Half hB) {
  int j = blockIdx.x;
  Half S = (j < 128) ? hA : hB;
  if (!S.active) return;
  int sub = j & 127;
  int rowblk = ((sub & 7) << 4) | (sub >> 3);   // XCD-pinned, 0..127
  int R = rowblk << 5;                           // 32 rows
  int tid = threadIdx.x;
  int l = tid & 63, w = tid >> 6;
  int rr = l & 15, ko = (l >> 4) << 3, q = l >> 4;
  int kb = w << 7;                               // 128-wide K slice
  const u16* __restrict__ Wh = S.Wh + (size_t)(R + rr) * 1024 + kb + ko;
  const u16* __restrict__ Wl = S.Wl + (size_t)(R + rr) * 1024 + kb + ko;
  const u16* __restrict__ Ah = S.Ah + kb + ko;
  const u16* __restrict__ Al = S.Al + kb + ko;

  f32x4 acc[8] = {};
#pragma unroll
  for (int kk = 0; kk < 128; kk += 32) {
    short8 bh[2], bl[2];
#pragma unroll
    for (int nt = 0; nt < 2; ++nt) {
      bh[nt] = *(const short8*)(Wh + (size_t)(nt << 4) * 1024 + kk);
      bl[nt] = *(const short8*)(Wl + (size_t)(nt << 4) * 1024 + kk);
    }
#pragma unroll
    for (int mt = 0; mt < 4; ++mt) {
      size_t ao = (size_t)((mt << 4) + rr) * 1024 + kk;
      short8 ah = *(const short8*)(Ah + ao);
      short8 al = *(const short8*)(Al + ao);
#pragma unroll
      for (int nt = 0; nt < 2; ++nt) {
        f32x4 t = acc[mt * 2 + nt];
        t = MFMA_BF16(ah, bh[nt], t, 0, 0, 0);
        t = MFMA_BF16(ah, bl[nt], t, 0, 0, 0);
        t = MFMA_BF16(al, bh[nt], t, 0, 0, 0);
        acc[mt * 2 + nt] = t;
      }
    }
  }

  __shared__ float lds[8][64][33];
#pragma unroll
  for (int mt = 0; mt < 4; ++mt)
#pragma unroll
    for (int nt = 0; nt < 2; ++nt)
#pragma unroll
      for (int r = 0; r < 4; ++r)
        lds[w][(mt << 4) + (q << 2) + r][(nt << 4) + rr] = acc[mt * 2 + nt][r];
  __syncthreads();

  int b = tid >> 3, e = tid & 7;
  float g[4];
#pragma unroll
  for (int gt = 0; gt < 4; ++gt) {
    int c = (e << 2) + gt;
    float s = S.bias[R + c] + S.pre[(size_t)b * 4096 + R + c];
#pragma unroll
    for (int ww = 0; ww < 8; ++ww) s += lds[ww][b][c];
    g[gt] = s;
  }
  int hc = (rowblk << 3) + e;
  size_t ci = (size_t)b * 1024 + hc;
  float cold = S.c[ci];
  float is = 1.f / (1.f + expf(-g[0]));
  float fs = 1.f / (1.f + expf(-g[1]));
  float gg = tanhf(g[2]);
  float os = 1.f / (1.f + expf(-g[3]));
  float cn = fs * cold + is * gg;
  S.c[ci] = cn;
  float h = os * tanhf(cn);
  S.Hh[ci] = f2bf(h);
  S.Hl[ci] = f2bf(h - bf2f(f2bf(h)));
}

// ---------------- decoder single-stage kernel ----------------
// 256 blocks; block = 16 perm-rows (4 h-cols). 8 waves = nops x K-slices.

struct Op { const u16 *Ah, *Al, *Wh, *Wl; };
struct Stage1 {
  Op ops[2];
  int nops;            // 1 or 2
  const float* pre;    // optional
  const float* bias;
  float* c;
  u16 *Hh, *Hl, *Gh, *Gl;
};

__global__ __launch_bounds__(512, 1) void lstm_one(Stage1 S) {
  int j = blockIdx.x;
  int rowblk = ((j & 7) << 5) | (j >> 3);      // XCD-pinned, 0..255
  int R = rowblk << 4;                          // 16 rows
  int tid = threadIdx.x;
  int l = tid & 63, w = tid >> 6;
  int rr = l & 15, ko = (l >> 4) << 3, q = l >> 4;
  int kslices = 8 / S.nops;
  int kwidth = 1024 / kslices;                  // 128 or 256
  Op op = S.ops[w / kslices];
  int kb = (w % kslices) * kwidth;
  const u16* __restrict__ Wh = op.Wh + (size_t)(R + rr) * 1024 + kb + ko;
  const u16* __restrict__ Wl = op.Wl + (size_t)(R + rr) * 1024 + kb + ko;
  const u16* __restrict__ Ah = op.Ah + kb + ko;
  const u16* __restrict__ Al = op.Al + kb + ko;

  f32x4 acc[4] = {};
#pragma unroll 2
  for (int kk = 0; kk < kwidth; kk += 32) {
    short8 bh = *(const short8*)(Wh + kk);
    short8 bl = *(const short8*)(Wl + kk);
#pragma unroll
    for (int mt = 0; mt < 4; ++mt) {
      size_t ao = (size_t)((mt << 4) + rr) * 1024 + kk;
      short8 ah = *(const short8*)(Ah + ao);
      short8 al = *(const short8*)(Al + ao);
      acc[mt] = MFMA_BF16(ah, bh, acc[mt], 0, 0, 0);
      acc[mt] = MFMA_BF16(ah, bl, acc[mt], 0, 0, 0);
      acc[mt] = MFMA_BF16(al, bh, acc[mt], 0, 0, 0);
    }
  }

  __shared__ float lds[8][64][17];
#pragma unroll
  for (int mt = 0; mt < 4; ++mt)
#pragma unroll
    for (int r = 0; r < 4; ++r)
      lds[w][(mt << 4) + (q << 2) + r][rr] = acc[mt][r];
  __syncthreads();

  if (tid < 256) {
    int b = tid >> 2, e = tid & 3;
    float g[4];
#pragma unroll
    for (int gt = 0; gt < 4; ++gt) {
      int c = (e << 2) + gt;
      float s = S.bias[R + c];
      if (S.pre) s += S.pre[(size_t)b * 4096 + R + c];
#pragma unroll
      for (int ww = 0; ww < 8; ++ww) s += lds[ww][b][c];
      g[gt] = s;
    }
    int hc = (rowblk << 2) + e;
    size_t ci = (size_t)b * 1024 + hc;
    float cold = S.c[ci];
    float is = 1.f / (1.f + expf(-g[0]));
    float fs = 1.f / (1.f + expf(-g[1]));
    float gg = tanhf(g[2]);
    float os = 1.f / (1.f + expf(-g[3]));
    float cn = fs * cold + is * gg;
    S.c[ci] = cn;
    float h = os * tanhf(cn);
    u16 hh = f2bf(h);
    u16 hl = f2bf(h - bf2f(hh));
    S.Hh[ci] = hh; S.Hl[ci] = hl;
    if (S.Gh) { S.Gh[ci] = hh; S.Gl[ci] = hl; }
  }
}

// ---------------- host ----------------

extern "C" void kernel_launch(void* const* d_in, const int* in_sizes, int n_in,
                              void* d_out, int out_size, void* d_ws, size_t ws_size,
                              hipStream_t stream) {
  (void)in_sizes; (void)n_in; (void)out_size; (void)ws_size;
  const float* input_seq = (const float*)d_in[0];
  const float* enc_wih   = (const float*)d_in[1];
  const float* enc_whh   = (const float*)d_in[2];
  const float* enc_b     = (const float*)d_in[3];
  const float* dec_wih   = (const float*)d_in[4];
  const float* dec_whh   = (const float*)d_in[5];
  const float* dec_b     = (const float*)d_in[6];
  const float* lin_w     = (const float*)d_in[7];
  const float* lin_b     = (const float*)d_in[8];
  float* out = (float*)d_out;

  const size_t WE = 4096ull * 1024;
  const size_t HB = 64ull * 1024;
  char* ws = (char*)d_ws;
  size_t off = 0;
  auto alloc16 = [&](size_t elems) {
    u16* p = (u16*)(ws + off);
    off = (off + elems * 2 + 255) & ~(size_t)255;
    return p;
  };
  auto allocf = [&](size_t elems) {
    float* p = (float*)(ws + off);
    off = (off + elems * 4 + 255) & ~(size_t)255;
    return p;
  };

  // weights (permuted rows) split hi/lo: 9 pairs x 16 MB = 144 MB
  u16 *WihE0h = alloc16(WE), *WihE0l = alloc16(WE);
  u16 *WhhE0h = alloc16(WE), *WhhE0l = alloc16(WE);
  u16 *WihE1h = alloc16(WE), *WihE1l = alloc16(WE);
  u16 *WhhE1h = alloc16(WE), *WhhE1l = alloc16(WE);
  u16 *WihD0h = alloc16(WE), *WihD0l = alloc16(WE);
  u16 *WhhD0h = alloc16(WE), *WhhD0l = alloc16(WE);
  u16 *WihD1h = alloc16(WE), *WihD1l = alloc16(WE);
  u16 *WhhD1h = alloc16(WE), *WhhD1l = alloc16(WE);
  u16 *Wcombh = alloc16(WE), *Wcombl = alloc16(WE);
  u16 *WLh  = alloc16(1024 * 1024), *WLl  = alloc16(1024 * 1024);
  u16 *WLTh = alloc16(1024 * 1024), *WLTl = alloc16(1024 * 1024);
  u16 *XCh = alloc16(16 * HB), *XCl = alloc16(16 * HB);     // x chunk
  u16 *XLh = alloc16(HB), *XLl = alloc16(HB);               // x_last
  u16 *H0ch = alloc16(17 * HB), *H0cl = alloc16(17 * HB);   // h0 ring
  u16 *H1h = alloc16(64 * HB), *H1l = alloc16(64 * HB);     // dec h1 history
  // zero region
  size_t zbeg = off;
  u16 *zh = alloc16(HB), *zl = alloc16(HB);
  float *c0 = allocf(HB), *c1 = allocf(HB);
  size_t zend = off;
  // ping-pong h slots
  u16 *e1h = alloc16(2 * HB), *e1l = alloc16(2 * HB);
  u16 *d0h = alloc16(2 * HB), *d0l = alloc16(2 * HB);
  u16 *d1h = alloc16(2 * HB), *d1l = alloc16(2 * HB);
  // gate buffers (fp32)
  float *G0 = allocf(1024ull * 4096);   // 16 MB
  float *G1 = allocf(1024ull * 4096);   // 16 MB
  float *Gd0 = allocf(64 * 4096);
  // biases
  float *ebp0 = allocf(4096), *ebp1 = allocf(4096);
  float *dbp0 = allocf(4096), *dbp1 = allocf(4096);
  float *bdec0 = allocf(4096);
  // total ~213 MB

  // 1) zeros
  {
    int n4 = (int)((zend - zbeg) / 16);
    zero_f4<<<dim3((n4 + 255) / 256), dim3(256), 0, stream>>>((float4*)(ws + zbeg), n4);
  }
  // 2) splits
  auto split = [&](const float* src, u16* dh, u16* dl, int n, int mode) {
    split_mat<<<dim3((n + 255) / 256), dim3(256), 0, stream>>>(src, dh, dl, n, mode);
  };
  split(enc_wih,        WihE0h, WihE0l, (int)WE, 2);
  split(enc_whh,        WhhE0h, WhhE0l, (int)WE, 2);
  split(enc_wih + WE,   WihE1h, WihE1l, (int)WE, 2);
  split(enc_whh + WE,   WhhE1h, WhhE1l, (int)WE, 2);
  split(dec_wih,        WihD0h, WihD0l, (int)WE, 2);
  split(dec_whh,        WhhD0h, WhhD0l, (int)WE, 2);
  split(dec_wih + WE,   WihD1h, WihD1l, (int)WE, 2);
  split(dec_whh + WE,   WhhD1h, WhhD1l, (int)WE, 2);
  split(lin_w, WLh,  WLl,  1024 * 1024, 0);
  split(lin_w, WLTh, WLTl, 1024 * 1024, 1);
  split(input_seq + 127ull * HB, XLh, XLl, (int)HB, 0);
  // 3) biases
  bias_perm<<<dim3(16), dim3(256), 0, stream>>>(enc_b,        ebp0);
  bias_perm<<<dim3(16), dim3(256), 0, stream>>>(enc_b + 4096, ebp1);
  bias_perm<<<dim3(16), dim3(256), 0, stream>>>(dec_b,        dbp0);
  bias_perm<<<dim3(16), dim3(256), 0, stream>>>(dec_b + 4096, dbp1);
  bias_comb<<<dim3(4096), dim3(256), 0, stream>>>(dec_b, lin_b, dec_wih, bdec0);
  // 4) Wcomb = WihD0(perm) @ lin_w : M=4096,N=1024 -> 32x8 blocks
  gemm_split<2><<<dim3(32 * 8), dim3(256), 0, stream>>>(
      WihD0h, WihD0l, 1024, WLTh, WLTl, 1024, 1024, 8,
      Wcombh, Wcombl, 1024, nullptr, nullptr, 0, 0);
  // 4b) Gd0 = x_last @ WihD0^T : M=64,N=4096 -> 1x32 blocks
  gemm_split<1><<<dim3(32), dim3(256), 0, stream>>>(
      XLh, XLl, 1024, WihD0h, WihD0l, 1024, 1024, 32,
      nullptr, nullptr, 0, Gd0, nullptr, 4096, 2);

  // 5) encoder: chunk ch: G0 gemm; paired steps L0(ch)+L1(ch-1); G1 gemm.
  for (int ch = 0; ch < 8; ++ch) {
    split(input_seq + (size_t)ch * 16 * HB, XCh, XCl, (int)(16 * HB), 0);
    gemm_split<2><<<dim3(8 * 32), dim3(256), 0, stream>>>(
        XCh, XCl, 1024, WihE0h, WihE0l, 1024, 1024, 32,
        nullptr, nullptr, 0, G0, nullptr, 4096, 2);
    for (int lt = 0; lt < 16; ++lt) {
      int t0 = ch * 16 + lt;               // L0 step index
      int t1 = (ch - 1) * 16 + lt;         // L1 step index (lagged)
      Half A;
      A.Ah = (t0 == 0) ? zh : (lt == 0 ? H0ch + 16ull * HB : H0ch + (size_t)lt * HB);
      A.Al = (t0 == 0) ? zl : (lt == 0 ? H0cl + 16ull * HB : H0cl + (size_t)lt * HB);
      A.Wh = WhhE0h; A.Wl = WhhE0l;
      A.pre = G0 + (size_t)lt * 64 * 4096;
      A.bias = ebp0; A.c = c0;
      A.Hh = H0ch + (size_t)(lt + 1) * HB; A.Hl = H0cl + (size_t)(lt + 1) * HB;
      A.active = 1;
      Half B;
      B.Ah = (t1 == 0) ? zh : e1h + (size_t)((t1 - 1) & 1) * HB;
      B.Al = (t1 == 0) ? zl : e1l + (size_t)((t1 - 1) & 1) * HB;
      B.Wh = WhhE1h; B.Wl = WhhE1l;
      B.pre = G1 + (size_t)lt * 64 * 4096;
      B.bias = ebp1; B.c = c1;
      B.Hh = e1h + (size_t)((t1 >= 0 ? t1 : 0) & 1) * HB;
      B.Hl = e1l + (size_t)((t1 >= 0 ? t1 : 0) & 1) * HB;
      B.active = (ch >= 1) ? 1 : 0;
      lstm_pair<<<dim3(256), dim3(512), 0, stream>>>(A, B);
    }
    gemm_split<2><<<dim3(8 * 32), dim3(256), 0, stream>>>(
        H0ch + HB, H0cl + HB, 1024, WihE1h, WihE1l, 1024, 1024, 32,
        nullptr, nullptr, 0, G1, nullptr, 4096, 2);
  }
  // drain: L1 steps for ch=7 (t1 = 112..127)
  for (int lt = 0; lt < 16; ++lt) {
    int t1 = 112 + lt;
    Half A; A.active = 0;
    A.Ah = zh; A.Al = zl; A.Wh = WhhE0h; A.Wl = WhhE0l;
    A.pre = G0; A.bias = ebp0; A.c = c0; A.Hh = H0ch; A.Hl = H0cl;
    Half B;
    B.Ah = e1h + (size_t)((t1 - 1) & 1) * HB;
    B.Al = e1l + (size_t)((t1 - 1) & 1) * HB;
    B.Wh = WhhE1h; B.Wl = WhhE1l;
    B.pre = G1 + (size_t)lt * 64 * 4096;
    B.bias = ebp1; B.c = c1;
    B.Hh = e1h + (size_t)(t1 & 1) * HB;
    B.Hl = e1l + (size_t)(t1 & 1) * HB;
    B.active = 1;
    lstm_pair<<<dim3(256), dim3(512), 0, stream>>>(A, B);
  }

  // 6) decoder: 64 steps x 2 sequential stages, 256 blocks each
  for (int t = 0; t < 64; ++t) {
    const u16 *h0p_h = (t == 0) ? H0ch + 16ull * HB : d0h + (size_t)((t - 1) & 1) * HB;
    const u16 *h0p_l = (t == 0) ? H0cl + 16ull * HB : d0l + (size_t)((t - 1) & 1) * HB;
    const u16 *h1p_h = (t == 0) ? e1h + HB : d1h + (size_t)((t - 1) & 1) * HB;
    const u16 *h1p_l = (t == 0) ? e1l + HB : d1l + (size_t)((t - 1) & 1) * HB;
    Stage1 A;
    if (t == 0) {
      A.ops[0] = {h0p_h, h0p_l, WhhD0h, WhhD0l};
      A.ops[1] = A.ops[0];
      A.nops = 1; A.pre = Gd0; A.bias = dbp0;
    } else {
      A.ops[0] = {h1p_h, h1p_l, Wcombh, Wcombl};
      A.ops[1] = {h0p_h, h0p_l, WhhD0h, WhhD0l};
      A.nops = 2; A.pre = nullptr; A.bias = bdec0;
    }
    A.c = c0;
    A.Hh = d0h + (size_t)(t & 1) * HB; A.Hl = d0l + (size_t)(t & 1) * HB;
    A.Gh = nullptr; A.Gl = nullptr;
    lstm_one<<<dim3(256), dim3(512), 0, stream>>>(A);
    Stage1 Bst;
    Bst.ops[0] = {d0h + (size_t)(t & 1) * HB, d0l + (size_t)(t & 1) * HB, WihD1h, WihD1l};
    Bst.ops[1] = {h1p_h, h1p_l, WhhD1h, WhhD1l};
    Bst.nops = 2; Bst.pre = nullptr; Bst.bias = dbp1; Bst.c = c1;
    Bst.Hh = d1h + (size_t)(t & 1) * HB; Bst.Hl = d1l + (size_t)(t & 1) * HB;
    Bst.Gh = H1h + (size_t)t * HB; Bst.Gl = H1l + (size_t)t * HB;
    lstm_one<<<dim3(256), dim3(512), 0, stream>>>(Bst);
  }

  // 7) y[b][t][o] = H1[t*64+b][:] . lin_w[o][:] + lin_b[o] : M=4096,N=1024
  gemm_split<2><<<dim3(32 * 8), dim3(256), 0, stream>>>(
      H1h, H1l, 1024, WLh, WLl, 1024, 1024, 8,
      nullptr, nullptr, 0, out, lin_b, 1024, 1);
}